// Round 2
// baseline (541.733 us; speedup 1.0000x reference)
//
#include <hip/hip_runtime.h>

typedef unsigned short u16;
typedef __attribute__((ext_vector_type(8))) short short8v;
typedef __attribute__((ext_vector_type(4))) float floatx4;

#define B_ 16
#define C_ 512
#define N_ 4096
#define K_ 128   // keys
#define NT 64    // pixels per block

__device__ __forceinline__ float bf2f(u16 u) {
    unsigned int x = ((unsigned int)u) << 16;
    return __builtin_bit_cast(float, x);
}
__device__ __forceinline__ u16 f2bf(float f) {
    unsigned int u = __builtin_bit_cast(unsigned int, f);
    u = u + 0x7FFFu + ((u >> 16) & 1u);
    return (u16)(u >> 16);
}

// ---------------------------------------------------------------------------
// P0: fp32 -> bf16 converts (y1,y2,wk1,wk2,wv1,wv2) + wq transpose, one launch
// ---------------------------------------------------------------------------
__global__ void conv_all(const float* __restrict__ y1, const float* __restrict__ y2,
                         const float* __restrict__ wk1, const float* __restrict__ wk2,
                         const float* __restrict__ wv1, const float* __restrict__ wv2,
                         const float* __restrict__ wq1, const float* __restrict__ wq2,
                         u16* y1b, u16* y2b, u16* wk1b, u16* wk2b, u16* wv1b, u16* wv2b,
                         u16* wq1t, u16* wq2t) {
    int tid = blockIdx.x * 256 + threadIdx.x;
    const int SY = B_ * K_ * C_;        // 1048576
    const int SWK = 256 * 512;          // 131072
    const int SWV = 512 * 512;          // 262144
    const int SQ = 128 * 512;           // 65536
    int base = 2*SY + 2*SWK + 2*SWV;    // 3014656 total with 2*SQ
    if (tid < base) {
        const float* src; u16* dst; int off;
        if (tid < SY)                 { src = y1;  dst = y1b;  off = tid; }
        else if (tid < 2*SY)          { src = y2;  dst = y2b;  off = tid - SY; }
        else if (tid < 2*SY+SWK)      { src = wk1; dst = wk1b; off = tid - 2*SY; }
        else if (tid < 2*SY+2*SWK)    { src = wk2; dst = wk2b; off = tid - 2*SY - SWK; }
        else if (tid < 2*SY+2*SWK+SWV){ src = wv1; dst = wv1b; off = tid - 2*SY - 2*SWK; }
        else                          { src = wv2; dst = wv2b; off = tid - 2*SY - 2*SWK - SWV; }
        dst[off] = f2bf(src[off]);
    } else {
        int e = tid - base;           // 0 .. 2*SQ-1
        const float* s = (e >= SQ) ? wq2 : wq1;
        u16* d = (e >= SQ) ? wq2t : wq1t;
        e &= (SQ - 1);
        int dd = e >> 9;              // 0..127
        int c = e & 511;              // coalesced read over c
        d[c * 128 + dd] = f2bf(s[dd * 512 + c]);
    }
}

// ---------------------------------------------------------------------------
// P1: k1b/k2b [b][key][256] = y @ wk^T + bk  AND  vt1/vt2 [b][c][128] = (y@wv^T+bv)^T
// flat grid 768 blocks x 64 threads
// ---------------------------------------------------------------------------
__global__ void gemm_gkgv(const u16* __restrict__ y1b, const u16* __restrict__ y2b,
                          const u16* __restrict__ wk1b, const u16* __restrict__ wk2b,
                          const u16* __restrict__ wv1b, const u16* __restrict__ wv2b,
                          const float* __restrict__ bk1, const float* __restrict__ bk2,
                          const float* __restrict__ bv1, const float* __restrict__ bv2,
                          u16* k1b, u16* k2b, u16* vt1, u16* vt2) {
    int l = threadIdx.x;
    int id = blockIdx.x;
    const u16 *A, *Bt; const float* bias; u16* outp;
    int m0, n0, po; bool bias_m;
    if (id < 256) {
        int bx = id & 1, by = (id >> 1) & 3, z = id >> 3;
        int b = z >> 1, which = z & 1;
        A = (which ? y2b : y1b) + (size_t)b * K_ * C_;
        Bt = which ? wk2b : wk1b;
        bias = which ? bk2 : bk1;
        outp = (which ? k2b : k1b) + (size_t)b * K_ * 256;
        m0 = bx * 64; n0 = by * 64; po = 256; bias_m = false;
    } else {
        int id2 = id - 256;
        int bx = id2 & 7, by = (id2 >> 3) & 1, z = id2 >> 4;
        int b = z >> 1, which = z & 1;
        A = which ? wv2b : wv1b;
        Bt = (which ? y2b : y1b) + (size_t)b * K_ * C_;
        bias = which ? bv2 : bv1;
        outp = (which ? vt2 : vt1) + (size_t)b * C_ * K_;
        m0 = bx * 64; n0 = by * 64; po = 128; bias_m = true;
    }
    floatx4 acc[4][4] = {};
    for (int ch = 0; ch < 16; ++ch) {
        int koff = ch * 32 + (l >> 4) * 8;
        short8v a[4], wv[4];
#pragma unroll
        for (int mf = 0; mf < 4; ++mf) a[mf] = *(const short8v*)(A + (size_t)(m0 + mf*16 + (l & 15)) * 512 + koff);
#pragma unroll
        for (int nf = 0; nf < 4; ++nf) wv[nf] = *(const short8v*)(Bt + (size_t)(n0 + nf*16 + (l & 15)) * 512 + koff);
#pragma unroll
        for (int mf = 0; mf < 4; ++mf)
#pragma unroll
            for (int nf = 0; nf < 4; ++nf)
                acc[mf][nf] = __builtin_amdgcn_mfma_f32_16x16x32_bf16(a[mf], wv[nf], acc[mf][nf], 0, 0, 0);
    }
#pragma unroll
    for (int mf = 0; mf < 4; ++mf)
#pragma unroll
        for (int nf = 0; nf < 4; ++nf)
#pragma unroll
            for (int rg = 0; rg < 4; ++rg) {
                int m = m0 + mf*16 + (l >> 4)*4 + rg;
                int n = n0 + nf*16 + (l & 15);
                outp[(size_t)m * po + n] = f2bf(acc[mf][nf][rg] + (bias_m ? bias[m] : bias[n]));
            }
}

// ---------------------------------------------------------------------------
// P2: ebias1/2[b][key] = bq_cat . k_row
// ---------------------------------------------------------------------------
__global__ void ebias_k(const u16* __restrict__ k1b, const u16* __restrict__ k2b,
                        const float* __restrict__ bq1, const float* __restrict__ bq2,
                        float* eb1, float* eb2) {
    int tid = blockIdx.x * 256 + threadIdx.x;  // 4096
    int pair = tid >> 11; int inner = tid & 2047;
    int b = inner >> 7; int key = inner & 127;
    const u16* kb = (pair ? k2b : k1b) + ((size_t)(b * 128 + key)) * 256;
    float s = 0.f;
    for (int d = 0; d < 128; ++d) s += bq1[d] * bf2f(kb[d]);
    for (int d = 0; d < 128; ++d) s += bq2[d] * bf2f(kb[128 + d]);
    (pair ? eb2 : eb1)[b * 128 + key] = s;
}

// ---------------------------------------------------------------------------
// P3: kk** [b][key][512] bf16: kk = k_half @ wqt^T(over d)
// grid (2, 8, 64) block 64    z = b*4 + which(0:kk11 1:kk12 2:kk21 3:kk22)
// ---------------------------------------------------------------------------
__global__ void gemm_gkk(const u16* __restrict__ k1b, const u16* __restrict__ k2b,
                         const u16* __restrict__ wq1t, const u16* __restrict__ wq2t,
                         u16* kk11, u16* kk12, u16* kk21, u16* kk22) {
    int l = threadIdx.x;
    int z = blockIdx.z; int b = z >> 2; int which = z & 3;
    const u16* A = ((which < 2) ? k1b : k2b) + (size_t)b * K_ * 256 + (which & 1) * 128;
    const u16* Wt = (which & 1) ? wq2t : wq1t;
    u16* outp;
    switch (which) { case 0: outp = kk11; break; case 1: outp = kk12; break;
                     case 2: outp = kk21; break; default: outp = kk22; }
    outp += (size_t)b * K_ * C_;
    int m0 = blockIdx.x * 64, n0 = blockIdx.y * 64;
    floatx4 acc[4][4] = {};
    for (int ch = 0; ch < 4; ++ch) {
        int koff = ch * 32 + (l >> 4) * 8;
        short8v a[4], wv[4];
#pragma unroll
        for (int mf = 0; mf < 4; ++mf) a[mf] = *(const short8v*)(A + (size_t)(m0 + mf*16 + (l & 15)) * 256 + koff);
#pragma unroll
        for (int nf = 0; nf < 4; ++nf) wv[nf] = *(const short8v*)(Wt + (size_t)(n0 + nf*16 + (l & 15)) * 128 + koff);
#pragma unroll
        for (int mf = 0; mf < 4; ++mf)
#pragma unroll
            for (int nf = 0; nf < 4; ++nf)
                acc[mf][nf] = __builtin_amdgcn_mfma_f32_16x16x32_bf16(a[mf], wv[nf], acc[mf][nf], 0, 0, 0);
    }
#pragma unroll
    for (int mf = 0; mf < 4; ++mf)
#pragma unroll
        for (int nf = 0; nf < 4; ++nf)
#pragma unroll
            for (int rg = 0; rg < 4; ++rg) {
                int m = m0 + mf*16 + (l >> 4)*4 + rg;
                int n = n0 + nf*16 + (l & 15);
                outp[(size_t)m * C_ + n] = f2bf(acc[mf][nf][rg]);
            }
}

// ---------------------------------------------------------------------------
// Main fused kernel: E = x.kk (K=1024), softmax(|e1-e2|), O = vt.attn^T, residual
// grid 1024, block 256 (4 waves), 3 blocks/CU
// kk/vt fragments have no cross-wave reuse -> loaded global->VGPR direct (L2-resident)
// ---------------------------------------------------------------------------
__global__ __launch_bounds__(256, 3)
void main_attn(const float* __restrict__ x1, const float* __restrict__ x2,
               const u16* __restrict__ kk11, const u16* __restrict__ kk12,
               const u16* __restrict__ kk21, const u16* __restrict__ kk22,
               const u16* __restrict__ vt1, const u16* __restrict__ vt2,
               const float* __restrict__ eb1, const float* __restrict__ eb2,
               const float* __restrict__ scale_p,
               float* __restrict__ out1, float* __restrict__ out2) {
    __shared__ float regionF[8768];       // 35072 B: xT[64][64]bf16 (8KB) | s_f[64][129]f32 + red1/red2
    __shared__ u16 attn_s[64 * 128];      // 16384 B, swizzled bf16 attn

    u16* xT = (u16*)regionF;              // pitch 64 shorts (128B), 8 granules/row
    float* s_f = regionF;                 // [64][129]
    float* red1 = regionF + 64 * 129;     // [4][64]
    float* red2 = red1 + 256;

    int bid0 = blockIdx.x;
    int bid = ((bid0 & 7) << 7) | (bid0 >> 3);   // XCD swizzle (1024 = 8*128, bijective)
    int b = bid >> 6;
    int n0 = (bid & 63) * NT;
    int t = threadIdx.x;
    int w = t >> 6;
    int l = t & 63;

    const float sc = scale_p[0];

    floatx4 e1a[4][2] = {}; floatx4 e2a[4][2] = {};

    const float* xs0 = x1 + (size_t)b * C_ * N_;
    const float* xs1 = x2 + (size_t)b * C_ * N_;
    const u16* kk11p = kk11 + (size_t)b * K_ * C_;
    const u16* kk12p = kk12 + (size_t)b * K_ * C_;
    const u16* kk21p = kk21 + (size_t)b * K_ * C_;
    const u16* kk22p = kk22 + (size_t)b * K_ * C_;

    float pv0[8], pv1[8];
    auto load_x = [&](int r) {
        int half = r >> 3;
        int c0 = (r & 7) * 64;
        const float* xp = (half ? xs1 : xs0) + (size_t)(c0 + w * 16 + (l >> 5) * 8) * N_ + n0 + 2 * (l & 31);
#pragma unroll
        for (int j = 0; j < 8; ++j) { float2 f = *(const float2*)(xp + (size_t)j * N_); pv0[j] = f.x; pv1[j] = f.y; }
    };

    load_x(0);
    for (int r = 0; r < 16; ++r) {
        if (r) __syncthreads();           // prior round's xT reads complete
        {   // write staged x -> xT (transpose + bf16), swizzled
            short8v p0, p1;
#pragma unroll
            for (int j = 0; j < 8; ++j) { p0[j] = (short)f2bf(pv0[j]); p1[j] = (short)f2bf(pv1[j]); }
            int row0 = 2 * (l & 31), row1 = row0 + 1;
            int g = w * 2 + (l >> 5);
            *(short8v*)&xT[row0 * 64 + 8 * (g ^ (row0 & 7))] = p0;
            *(short8v*)&xT[row1 * 64 + 8 * (g ^ (row1 & 7))] = p1;
        }
        __syncthreads();
        if (r < 15) load_x(r + 1);        // T14: next-round x loads overlap MFMA below

        int half = r >> 3;
        int c0 = (r & 7) * 64;
        const u16* kkA = half ? kk12p : kk11p;
        const u16* kkB = half ? kk22p : kk21p;
#pragma unroll
        for (int ch = 0; ch < 2; ++ch) {
            short8v a[4];
#pragma unroll
            for (int mf = 0; mf < 4; ++mf) {
                int row = mf * 16 + (l & 15);
                int g = ch * 4 + (l >> 4);
                a[mf] = *(const short8v*)&xT[row * 64 + 8 * (g ^ (row & 7))];
            }
#pragma unroll
            for (int kf = 0; kf < 2; ++kf) {
                size_t off = (size_t)(w * 32 + kf * 16 + (l & 15)) * 512 + c0 + ch * 32 + (l >> 4) * 8;
                short8v b1 = *(const short8v*)(kkA + off);
                short8v b2 = *(const short8v*)(kkB + off);
#pragma unroll
                for (int mf = 0; mf < 4; ++mf) {
                    e1a[mf][kf] = __builtin_amdgcn_mfma_f32_16x16x32_bf16(a[mf], b1, e1a[mf][kf], 0, 0, 0);
                    e2a[mf][kf] = __builtin_amdgcn_mfma_f32_16x16x32_bf16(a[mf], b2, e2a[mf][kf], 0, 0, 0);
                }
            }
        }
    }
    __syncthreads();                      // last xT reads done before s_f overlays

    // ---- softmax over keys of |e1 - e2| (with folded q-bias terms)
    float ebv1[2], ebv2[2];
#pragma unroll
    for (int kf = 0; kf < 2; ++kf) {
        int kc = w * 32 + kf * 16 + (l & 15);
        ebv1[kf] = eb1[b * 128 + kc];
        ebv2[kf] = eb2[b * 128 + kc];
    }
#pragma unroll
    for (int mf = 0; mf < 4; ++mf)
#pragma unroll
        for (int kf = 0; kf < 2; ++kf)
#pragma unroll
            for (int rg = 0; rg < 4; ++rg) {
                int row = mf * 16 + (l >> 4) * 4 + rg;
                int col = w * 32 + kf * 16 + (l & 15);
                s_f[row * 129 + col] = fabsf(e1a[mf][kf][rg] + ebv1[kf] - e2a[mf][kf][rg] - ebv2[kf]);
            }
    __syncthreads();
    {
        int rrow = l; int q = w;
        float m = -1e30f;
        for (int i = 0; i < 32; ++i) m = fmaxf(m, s_f[rrow * 129 + q * 32 + i]);
        red1[q * 64 + rrow] = m;
        __syncthreads();
        float mrow = fmaxf(fmaxf(red1[rrow], red1[64 + rrow]), fmaxf(red1[128 + rrow], red1[192 + rrow]));
        float ps = 0.f;
        for (int i = 0; i < 32; ++i) {
            float e = __expf(s_f[rrow * 129 + q * 32 + i] - mrow);
            s_f[rrow * 129 + q * 32 + i] = e;
            ps += e;
        }
        red2[q * 64 + rrow] = ps;
        __syncthreads();
        float inv = 1.0f / (red2[rrow] + red2[64 + rrow] + red2[128 + rrow] + red2[192 + rrow]);
#pragma unroll
        for (int g2 = 0; g2 < 4; ++g2) {
            int g = q * 4 + g2;
            short8v pk;
#pragma unroll
            for (int j = 0; j < 8; ++j) pk[j] = (short)f2bf(s_f[rrow * 129 + g * 8 + j] * inv);
            *(short8v*)&attn_s[rrow * 128 + 8 * (g ^ (rrow & 7))] = pk;
        }
    }
    __syncthreads();

    // ---- PV: O[c][n] = vt[c][k] . attn[n][k], + residual.  No barriers; vt direct from L2.
    for (int oi = 0; oi < 2; ++oi) {
        const u16* vt = (oi ? vt2 : vt1) + (size_t)b * C_ * K_;
        const float* xr = oi ? xs1 : xs0;
        float* op = (oi ? out2 : out1) + (size_t)b * C_ * N_;
#pragma unroll
        for (int cc = 0; cc < 4; ++cc) {
            floatx4 o[2][4] = {};
#pragma unroll
            for (int kc = 0; kc < 4; ++kc) {
                short8v a[2];
#pragma unroll
                for (int mf = 0; mf < 2; ++mf) {
                    size_t row = cc * 128 + w * 32 + mf * 16 + (l & 15);
                    a[mf] = *(const short8v*)(vt + row * K_ + kc * 32 + (l >> 4) * 8);
                }
#pragma unroll
                for (int nf = 0; nf < 4; ++nf) {
                    int nrow = nf * 16 + (l & 15);
                    int g = kc * 4 + (l >> 4);
                    short8v bb = *(const short8v*)&attn_s[nrow * 128 + 8 * (g ^ (nrow & 7))];
#pragma unroll
                    for (int mf = 0; mf < 2; ++mf)
                        o[mf][nf] = __builtin_amdgcn_mfma_f32_16x16x32_bf16(a[mf], bb, o[mf][nf], 0, 0, 0);
                }
            }
#pragma unroll
            for (int mf = 0; mf < 2; ++mf)
#pragma unroll
                for (int nf = 0; nf < 4; ++nf)
#pragma unroll
                    for (int rg = 0; rg < 4; ++rg) {
                        int c = cc * 128 + w * 32 + mf * 16 + (l >> 4) * 4 + rg;
                        int n = n0 + nf * 16 + (l & 15);
                        size_t idx = (size_t)c * N_ + n;
                        op[idx] = sc * o[mf][nf][rg] + xr[idx];
                    }
        }
    }
}

// ---------------------------------------------------------------------------
extern "C" void kernel_launch(void* const* d_in, const int* in_sizes, int n_in,
                              void* d_out, int out_size, void* d_ws, size_t ws_size,
                              hipStream_t stream) {
    const float* x1 = (const float*)d_in[0];
    const float* y1 = (const float*)d_in[1];
    const float* x2 = (const float*)d_in[2];
    const float* y2 = (const float*)d_in[3];
    const float* wq1 = (const float*)d_in[4];
    const float* bq1 = (const float*)d_in[5];
    const float* wq2 = (const float*)d_in[6];
    const float* bq2 = (const float*)d_in[7];
    const float* wk1 = (const float*)d_in[8];
    const float* bk1 = (const float*)d_in[9];
    const float* wk2 = (const float*)d_in[10];
    const float* bk2 = (const float*)d_in[11];
    const float* wv1 = (const float*)d_in[12];
    const float* bv1 = (const float*)d_in[13];
    const float* wv2 = (const float*)d_in[14];
    const float* bv2 = (const float*)d_in[15];
    const float* scale = (const float*)d_in[16];

    char* ws = (char*)d_ws;
    u16* y1b  = (u16*)(ws + 0);
    u16* y2b  = (u16*)(ws + 2097152);
    u16* wk1b = (u16*)(ws + 4194304);
    u16* wk2b = (u16*)(ws + 4456448);
    u16* wv1b = (u16*)(ws + 4718592);
    u16* wv2b = (u16*)(ws + 5242880);
    u16* wq1t = (u16*)(ws + 5767168);
    u16* wq2t = (u16*)(ws + 5898240);
    u16* k1b  = (u16*)(ws + 6029312);
    u16* k2b  = (u16*)(ws + 7077888);
    u16* kk11 = (u16*)(ws + 8126464);
    u16* kk12 = (u16*)(ws + 10223616);
    u16* kk21 = (u16*)(ws + 12320768);
    u16* kk22 = (u16*)(ws + 14417920);
    u16* vt1  = (u16*)(ws + 16515072);
    u16* vt2  = (u16*)(ws + 18612224);
    float* eb1 = (float*)(ws + 20709376);
    float* eb2 = (float*)(ws + 20717568);

    float* out1 = (float*)d_out;
    float* out2 = out1 + (size_t)B_ * C_ * N_;

    hipLaunchKernelGGL(conv_all, dim3(11776), dim3(256), 0, stream,
                       y1, y2, wk1, wk2, wv1, wv2, wq1, wq2,
                       y1b, y2b, wk1b, wk2b, wv1b, wv2b, wq1t, wq2t);
    hipLaunchKernelGGL(gemm_gkgv, dim3(768), dim3(64), 0, stream,
                       y1b, y2b, wk1b, wk2b, wv1b, wv2b, bk1, bk2, bv1, bv2,
                       k1b, k2b, vt1, vt2);
    hipLaunchKernelGGL(ebias_k, dim3(16), dim3(256), 0, stream, k1b, k2b, bq1, bq2, eb1, eb2);
    hipLaunchKernelGGL(gemm_gkk, dim3(2, 8, 64), dim3(64), 0, stream,
                       k1b, k2b, wq1t, wq2t, kk11, kk12, kk21, kk22);
    hipLaunchKernelGGL(main_attn, dim3(1024), dim3(256), 0, stream,
                       x1, x2, kk11, kk12, kk21, kk22, vt1, vt2, eb1, eb2, scale,
                       out1, out2);
}

// Round 3
// 240.478 us; speedup vs baseline: 2.2527x; 2.2527x over previous
//
#include <hip/hip_runtime.h>

typedef unsigned short u16;
typedef __attribute__((ext_vector_type(8))) short short8v;
typedef __attribute__((ext_vector_type(4))) float floatx4;

#define B_ 16
#define C_ 512
#define N_ 4096
#define K_ 128   // keys
#define NT 64    // pixels per block

__device__ __forceinline__ float bf2f(u16 u) {
    unsigned int x = ((unsigned int)u) << 16;
    return __builtin_bit_cast(float, x);
}
__device__ __forceinline__ u16 f2bf(float f) {
    unsigned int u = __builtin_bit_cast(unsigned int, f);
    u = u + 0x7FFFu + ((u >> 16) & 1u);
    return (u16)(u >> 16);
}

// ---------------------------------------------------------------------------
// P0: fp32 -> bf16 converts (y1,y2,wk1,wk2,wv1,wv2) + wq transpose, one launch
// ---------------------------------------------------------------------------
__global__ void conv_all(const float* __restrict__ y1, const float* __restrict__ y2,
                         const float* __restrict__ wk1, const float* __restrict__ wk2,
                         const float* __restrict__ wv1, const float* __restrict__ wv2,
                         const float* __restrict__ wq1, const float* __restrict__ wq2,
                         u16* y1b, u16* y2b, u16* wk1b, u16* wk2b, u16* wv1b, u16* wv2b,
                         u16* wq1t, u16* wq2t) {
    int tid = blockIdx.x * 256 + threadIdx.x;
    const int SY = B_ * K_ * C_;        // 1048576
    const int SWK = 256 * 512;          // 131072
    const int SWV = 512 * 512;          // 262144
    const int SQ = 128 * 512;           // 65536
    int base = 2*SY + 2*SWK + 2*SWV;
    if (tid < base) {
        const float* src; u16* dst; int off;
        if (tid < SY)                 { src = y1;  dst = y1b;  off = tid; }
        else if (tid < 2*SY)          { src = y2;  dst = y2b;  off = tid - SY; }
        else if (tid < 2*SY+SWK)      { src = wk1; dst = wk1b; off = tid - 2*SY; }
        else if (tid < 2*SY+2*SWK)    { src = wk2; dst = wk2b; off = tid - 2*SY - SWK; }
        else if (tid < 2*SY+2*SWK+SWV){ src = wv1; dst = wv1b; off = tid - 2*SY - 2*SWK; }
        else                          { src = wv2; dst = wv2b; off = tid - 2*SY - 2*SWK - SWV; }
        dst[off] = f2bf(src[off]);
    } else {
        int e = tid - base;           // 0 .. 2*SQ-1
        const float* s = (e >= SQ) ? wq2 : wq1;
        u16* d = (e >= SQ) ? wq2t : wq1t;
        e &= (SQ - 1);
        int dd = e >> 9;              // 0..127
        int c = e & 511;              // coalesced read over c
        d[c * 128 + dd] = f2bf(s[dd * 512 + c]);
    }
}

// ---------------------------------------------------------------------------
// P1: k1b/k2b [b][key][256] = y @ wk^T + bk  AND  vt1/vt2 [b][c][128] = (y@wv^T+bv)^T
// flat grid 768 blocks x 64 threads
// ---------------------------------------------------------------------------
__global__ void gemm_gkgv(const u16* __restrict__ y1b, const u16* __restrict__ y2b,
                          const u16* __restrict__ wk1b, const u16* __restrict__ wk2b,
                          const u16* __restrict__ wv1b, const u16* __restrict__ wv2b,
                          const float* __restrict__ bk1, const float* __restrict__ bk2,
                          const float* __restrict__ bv1, const float* __restrict__ bv2,
                          u16* k1b, u16* k2b, u16* vt1, u16* vt2) {
    int l = threadIdx.x;
    int id = blockIdx.x;
    const u16 *A, *Bt; const float* bias; u16* outp;
    int m0, n0, po; bool bias_m;
    if (id < 256) {
        int bx = id & 1, by = (id >> 1) & 3, z = id >> 3;
        int b = z >> 1, which = z & 1;
        A = (which ? y2b : y1b) + (size_t)b * K_ * C_;
        Bt = which ? wk2b : wk1b;
        bias = which ? bk2 : bk1;
        outp = (which ? k2b : k1b) + (size_t)b * K_ * 256;
        m0 = bx * 64; n0 = by * 64; po = 256; bias_m = false;
    } else {
        int id2 = id - 256;
        int bx = id2 & 7, by = (id2 >> 3) & 1, z = id2 >> 4;
        int b = z >> 1, which = z & 1;
        A = which ? wv2b : wv1b;
        Bt = (which ? y2b : y1b) + (size_t)b * K_ * C_;
        bias = which ? bv2 : bv1;
        outp = (which ? vt2 : vt1) + (size_t)b * C_ * K_;
        m0 = bx * 64; n0 = by * 64; po = 128; bias_m = true;
    }
    floatx4 acc[4][4] = {};
    for (int ch = 0; ch < 16; ++ch) {
        int koff = ch * 32 + (l >> 4) * 8;
        short8v a[4], wv[4];
#pragma unroll
        for (int mf = 0; mf < 4; ++mf) a[mf] = *(const short8v*)(A + (size_t)(m0 + mf*16 + (l & 15)) * 512 + koff);
#pragma unroll
        for (int nf = 0; nf < 4; ++nf) wv[nf] = *(const short8v*)(Bt + (size_t)(n0 + nf*16 + (l & 15)) * 512 + koff);
#pragma unroll
        for (int mf = 0; mf < 4; ++mf)
#pragma unroll
            for (int nf = 0; nf < 4; ++nf)
                acc[mf][nf] = __builtin_amdgcn_mfma_f32_16x16x32_bf16(a[mf], wv[nf], acc[mf][nf], 0, 0, 0);
    }
#pragma unroll
    for (int mf = 0; mf < 4; ++mf)
#pragma unroll
        for (int nf = 0; nf < 4; ++nf)
#pragma unroll
            for (int rg = 0; rg < 4; ++rg) {
                int m = m0 + mf*16 + (l >> 4)*4 + rg;
                int n = n0 + nf*16 + (l & 15);
                outp[(size_t)m * po + n] = f2bf(acc[mf][nf][rg] + (bias_m ? bias[m] : bias[n]));
            }
}

// ---------------------------------------------------------------------------
// P2: kd = k1b - k2b  (bf16), 524288 elems
// ---------------------------------------------------------------------------
__global__ void kd_sub(const u16* __restrict__ k1b, const u16* __restrict__ k2b,
                       u16* kd) {
    int tid = blockIdx.x * 256 + threadIdx.x;
    kd[tid] = f2bf(bf2f(k1b[tid]) - bf2f(k2b[tid]));
}

// P2b: ebd[b*128+key] = bq_cat . kd_row
__global__ void ebd_k(const u16* __restrict__ kd,
                      const float* __restrict__ bq1, const float* __restrict__ bq2,
                      float* ebd) {
    int tid = blockIdx.x * 256 + threadIdx.x;  // 2048
    const u16* kb = kd + (size_t)tid * 256;
    float s = 0.f;
    for (int d = 0; d < 128; ++d) s += bq1[d] * bf2f(kb[d]);
    for (int d = 0; d < 128; ++d) s += bq2[d] * bf2f(kb[128 + d]);
    ebd[tid] = s;
}

// ---------------------------------------------------------------------------
// P3: kkd1/kkd2 [b][key][512] bf16 = kd_half @ wqt^T (K=128 over d)
// grid (2, 8, 32) block 64; z = b*2 + which
// ---------------------------------------------------------------------------
__global__ void gemm_gkk(const u16* __restrict__ kd,
                         const u16* __restrict__ wq1t, const u16* __restrict__ wq2t,
                         u16* kkd1, u16* kkd2) {
    int l = threadIdx.x;
    int z = blockIdx.z; int b = z >> 1; int which = z & 1;
    const u16* A = kd + (size_t)b * K_ * 256 + which * 128;
    const u16* Wt = which ? wq2t : wq1t;
    u16* outp = (which ? kkd2 : kkd1) + (size_t)b * K_ * C_;
    int m0 = blockIdx.x * 64, n0 = blockIdx.y * 64;
    floatx4 acc[4][4] = {};
    for (int ch = 0; ch < 4; ++ch) {
        int koff = ch * 32 + (l >> 4) * 8;
        short8v a[4], wv[4];
#pragma unroll
        for (int mf = 0; mf < 4; ++mf) a[mf] = *(const short8v*)(A + (size_t)(m0 + mf*16 + (l & 15)) * 256 + koff);
#pragma unroll
        for (int nf = 0; nf < 4; ++nf) wv[nf] = *(const short8v*)(Wt + (size_t)(n0 + nf*16 + (l & 15)) * 128 + koff);
#pragma unroll
        for (int mf = 0; mf < 4; ++mf)
#pragma unroll
            for (int nf = 0; nf < 4; ++nf)
                acc[mf][nf] = __builtin_amdgcn_mfma_f32_16x16x32_bf16(a[mf], wv[nf], acc[mf][nf], 0, 0, 0);
    }
#pragma unroll
    for (int mf = 0; mf < 4; ++mf)
#pragma unroll
        for (int nf = 0; nf < 4; ++nf)
#pragma unroll
            for (int rg = 0; rg < 4; ++rg) {
                int m = m0 + mf*16 + (l >> 4)*4 + rg;
                int n = n0 + nf*16 + (l & 15);
                outp[(size_t)m * C_ + n] = f2bf(acc[mf][nf][rg]);
            }
}

// ---------------------------------------------------------------------------
// Main fused kernel: ediff = x.kkd (K=1024) + ebd, softmax(|ediff|), O = vt.attn^T, residual
// grid 1024, block 256 (4 waves). Double-buffered xT, reg-prefetched kk frags,
// in-register softmax, barrier-free PV. LDS 33.25KB -> 3+ blocks/CU.
// ---------------------------------------------------------------------------
__global__ __launch_bounds__(256, 3)
void main_attn(const float* __restrict__ x1, const float* __restrict__ x2,
               const u16* __restrict__ kkd1, const u16* __restrict__ kkd2,
               const u16* __restrict__ vt1, const u16* __restrict__ vt2,
               const float* __restrict__ ebd,
               const float* __restrict__ scale_p,
               float* __restrict__ out1, float* __restrict__ out2) {
    __shared__ u16 xTb[2][4096];      // 16KB: [64 n][64 c] bf16, swizzled, double-buffered
    __shared__ u16 attn_s[8192];      // 16KB: [64 n][128 k] bf16, swizzled
    __shared__ float redA[256];       // per-wave row partials
    __shared__ float redM[64];        // combined row max / sum

    int bid0 = blockIdx.x;
    int bid = ((bid0 & 7) << 7) | (bid0 >> 3);   // XCD swizzle (1024 = 8*128, bijective)
    int b = bid >> 6;
    int n0 = (bid & 63) * NT;
    int t = threadIdx.x;
    int w = t >> 6;
    int l = t & 63;

    const float sc = scale_p[0];
    const float* xs0 = x1 + (size_t)b * C_ * N_;
    const float* xs1 = x2 + (size_t)b * C_ * N_;
    const u16* kkp[2] = { kkd1 + (size_t)b * K_ * C_, kkd2 + (size_t)b * K_ * C_ };

    floatx4 ed[4][2] = {};            // ediff acc: rows 64 x keys (w*32 + kf*16 + lane)

    float pvA0[8], pvA1[8], pvB0[8], pvB1[8];
    short8v kkA[2][2], kkB[2][2];     // [kf][ch]

    auto LOADX = [&](int r, float (&v0)[8], float (&v1)[8]) {
        const float* xp = (r >= 8 ? xs1 : xs0) + (size_t)((r & 7) * 64 + w * 16 + (l >> 5) * 8) * N_ + n0 + 2 * (l & 31);
#pragma unroll
        for (int j = 0; j < 8; ++j) { float2 f = *(const float2*)(xp + (size_t)j * N_); v0[j] = f.x; v1[j] = f.y; }
    };
    auto LOADK = [&](int r, short8v (&kkf)[2][2]) {
        const u16* base = kkp[r >> 3] + (size_t)(w * 32 + (l & 15)) * 512 + (r & 7) * 64 + (l >> 4) * 8;
#pragma unroll
        for (int kf = 0; kf < 2; ++kf)
#pragma unroll
            for (int ch = 0; ch < 2; ++ch)
                kkf[kf][ch] = *(const short8v*)(base + kf * 16 * 512 + ch * 32);
    };
    auto WRITEXT = [&](u16* xbuf, float (&v0)[8], float (&v1)[8]) {
        short8v p0, p1;
#pragma unroll
        for (int j = 0; j < 8; ++j) { p0[j] = (short)f2bf(v0[j]); p1[j] = (short)f2bf(v1[j]); }
        int row0 = 2 * (l & 31);
        int sw = 8 * ((w * 2 + (l >> 5)) ^ ((l & 31) & 7));
        *(short8v*)&xbuf[row0 * 64 + sw] = p0;
        *(short8v*)&xbuf[(row0 + 1) * 64 + sw] = p1;
    };
    auto EMM = [&](const u16* xbuf, short8v (&kkf)[2][2]) {
#pragma unroll
        for (int ch = 0; ch < 2; ++ch) {
            short8v a[4];
#pragma unroll
            for (int mf = 0; mf < 4; ++mf) {
                int row = mf * 16 + (l & 15);
                int g = ch * 4 + (l >> 4);
                a[mf] = *(const short8v*)&xbuf[row * 64 + 8 * (g ^ ((row >> 1) & 7))];
            }
#pragma unroll
            for (int kf = 0; kf < 2; ++kf)
#pragma unroll
                for (int mf = 0; mf < 4; ++mf)
                    ed[mf][kf] = __builtin_amdgcn_mfma_f32_16x16x32_bf16(a[mf], kkf[kf][ch], ed[mf][kf], 0, 0, 0);
        }
    };

    // ---- E phase: 16 rounds of 64 channels, 1 barrier/round, 1-round prefetch
    LOADX(0, pvA0, pvA1); LOADK(0, kkA);
    WRITEXT(xTb[0], pvA0, pvA1);
    LOADX(1, pvB0, pvB1); LOADK(1, kkB);
#pragma unroll
    for (int rr = 0; rr < 8; ++rr) {
        int rA = 2 * rr, rB = 2 * rr + 1;
        __syncthreads();
        EMM(xTb[0], kkA);                      // round rA (even -> buf 0)
        WRITEXT(xTb[1], pvB0, pvB1);           // data for round rB
        if (rA + 2 <= 15) { LOADX(rA + 2, pvA0, pvA1); LOADK(rA + 2, kkA); }
        __syncthreads();
        EMM(xTb[1], kkB);                      // round rB (odd -> buf 1)
        if (rB + 1 <= 15) WRITEXT(xTb[0], pvA0, pvA1);
        if (rB + 2 <= 15) { LOADX(rB + 2, pvB0, pvB1); LOADK(rB + 2, kkB); }
    }

    // ---- in-register softmax over keys of |ediff + ebd|
    float ebdv[2];
#pragma unroll
    for (int kf = 0; kf < 2; ++kf) ebdv[kf] = ebd[b * 128 + w * 32 + kf * 16 + (l & 15)];
#pragma unroll
    for (int mf = 0; mf < 4; ++mf)
#pragma unroll
        for (int kf = 0; kf < 2; ++kf)
#pragma unroll
            for (int rg = 0; rg < 4; ++rg)
                ed[mf][kf][rg] = fabsf(ed[mf][kf][rg] + ebdv[kf]);

    float m16[16];
#pragma unroll
    for (int mf = 0; mf < 4; ++mf)
#pragma unroll
        for (int rg = 0; rg < 4; ++rg)
            m16[mf * 4 + rg] = fmaxf(ed[mf][0][rg], ed[mf][1][rg]);
#pragma unroll
    for (int st = 1; st < 16; st <<= 1)
#pragma unroll
        for (int i = 0; i < 16; ++i)
            m16[i] = fmaxf(m16[i], __shfl_xor(m16[i], st));
    if ((l & 15) == 0) {
#pragma unroll
        for (int mf = 0; mf < 4; ++mf)
#pragma unroll
            for (int rg = 0; rg < 4; ++rg)
                redA[w * 64 + mf * 16 + (l >> 4) * 4 + rg] = m16[mf * 4 + rg];
    }
    __syncthreads();
    if (t < 64) redM[t] = fmaxf(fmaxf(redA[t], redA[64 + t]), fmaxf(redA[128 + t], redA[192 + t]));
    __syncthreads();

    float s16[16];
#pragma unroll
    for (int mf = 0; mf < 4; ++mf)
#pragma unroll
        for (int rg = 0; rg < 4; ++rg) {
            float mr = redM[mf * 16 + (l >> 4) * 4 + rg];
            float e0 = __expf(ed[mf][0][rg] - mr);
            float e1 = __expf(ed[mf][1][rg] - mr);
            ed[mf][0][rg] = e0; ed[mf][1][rg] = e1;
            s16[mf * 4 + rg] = e0 + e1;
        }
#pragma unroll
    for (int st = 1; st < 16; st <<= 1)
#pragma unroll
        for (int i = 0; i < 16; ++i)
            s16[i] += __shfl_xor(s16[i], st);
    if ((l & 15) == 0) {
#pragma unroll
        for (int mf = 0; mf < 4; ++mf)
#pragma unroll
            for (int rg = 0; rg < 4; ++rg)
                redA[w * 64 + mf * 16 + (l >> 4) * 4 + rg] = s16[mf * 4 + rg];
    }
    __syncthreads();
    if (t < 64) redM[t] = redA[t] + redA[64 + t] + redA[128 + t] + redA[192 + t];
    __syncthreads();

#pragma unroll
    for (int mf = 0; mf < 4; ++mf)
#pragma unroll
        for (int rg = 0; rg < 4; ++rg) {
            int row = mf * 16 + (l >> 4) * 4 + rg;
            float inv = 1.0f / redM[row];
#pragma unroll
            for (int kf = 0; kf < 2; ++kf) {
                int col = w * 32 + kf * 16 + (l & 15);
                attn_s[row * 128 + 8 * ((col >> 3) ^ (row & 7)) + (col & 7)] = f2bf(ed[mf][kf][rg] * inv);
            }
        }
    __syncthreads();

    // ---- PV: O[c][n] = vt[c][k] . attn[n][k], + residual; vt/residual batch-loaded at chunk top
    const u16* vt1p = vt1 + (size_t)b * C_ * K_;
    const u16* vt2p = vt2 + (size_t)b * C_ * K_;
    float* out1p = out1 + (size_t)b * C_ * N_;
    float* out2p = out2 + (size_t)b * C_ * N_;
    for (int q = 0; q < 8; ++q) {
        int oi = q >> 2, cc = q & 3;
        const u16* vt = oi ? vt2p : vt1p;
        const float* xr = oi ? xs1 : xs0;
        float* op = oi ? out2p : out1p;
        short8v vf[2][4];
#pragma unroll
        for (int mf = 0; mf < 2; ++mf)
#pragma unroll
            for (int kc = 0; kc < 4; ++kc)
                vf[mf][kc] = *(const short8v*)(vt + (size_t)(cc * 128 + w * 32 + mf * 16 + (l & 15)) * K_ + kc * 32 + (l >> 4) * 8);
        float resv[2][4][4];
#pragma unroll
        for (int mf = 0; mf < 2; ++mf)
#pragma unroll
            for (int rg = 0; rg < 4; ++rg)
#pragma unroll
                for (int nf = 0; nf < 4; ++nf)
                    resv[mf][rg][nf] = xr[(size_t)(cc * 128 + w * 32 + mf * 16 + (l >> 4) * 4 + rg) * N_ + n0 + nf * 16 + (l & 15)];
        floatx4 o[2][4] = {};
#pragma unroll
        for (int kc = 0; kc < 4; ++kc) {
            short8v bb[4];
#pragma unroll
            for (int nf = 0; nf < 4; ++nf) {
                int nrow = nf * 16 + (l & 15);
                int g = kc * 4 + (l >> 4);
                bb[nf] = *(const short8v*)&attn_s[nrow * 128 + 8 * (g ^ (nrow & 7))];
            }
#pragma unroll
            for (int nf = 0; nf < 4; ++nf)
#pragma unroll
                for (int mf = 0; mf < 2; ++mf)
                    o[mf][nf] = __builtin_amdgcn_mfma_f32_16x16x32_bf16(vf[mf][kc], bb[nf], o[mf][nf], 0, 0, 0);
        }
#pragma unroll
        for (int mf = 0; mf < 2; ++mf)
#pragma unroll
            for (int rg = 0; rg < 4; ++rg)
#pragma unroll
                for (int nf = 0; nf < 4; ++nf) {
                    size_t idx = (size_t)(cc * 128 + w * 32 + mf * 16 + (l >> 4) * 4 + rg) * N_ + n0 + nf * 16 + (l & 15);
                    op[idx] = sc * o[mf][nf][rg] + resv[mf][rg][nf];
                }
    }
}

// ---------------------------------------------------------------------------
extern "C" void kernel_launch(void* const* d_in, const int* in_sizes, int n_in,
                              void* d_out, int out_size, void* d_ws, size_t ws_size,
                              hipStream_t stream) {
    const float* x1 = (const float*)d_in[0];
    const float* y1 = (const float*)d_in[1];
    const float* x2 = (const float*)d_in[2];
    const float* y2 = (const float*)d_in[3];
    const float* wq1 = (const float*)d_in[4];
    const float* bq1 = (const float*)d_in[5];
    const float* wq2 = (const float*)d_in[6];
    const float* bq2 = (const float*)d_in[7];
    const float* wk1 = (const float*)d_in[8];
    const float* bk1 = (const float*)d_in[9];
    const float* wk2 = (const float*)d_in[10];
    const float* bk2 = (const float*)d_in[11];
    const float* wv1 = (const float*)d_in[12];
    const float* bv1 = (const float*)d_in[13];
    const float* wv2 = (const float*)d_in[14];
    const float* bv2 = (const float*)d_in[15];
    const float* scale = (const float*)d_in[16];

    char* ws = (char*)d_ws;
    u16* y1b  = (u16*)(ws + 0);
    u16* y2b  = (u16*)(ws + 2097152);
    u16* wk1b = (u16*)(ws + 4194304);
    u16* wk2b = (u16*)(ws + 4456448);
    u16* wv1b = (u16*)(ws + 4718592);
    u16* wv2b = (u16*)(ws + 5242880);
    u16* wq1t = (u16*)(ws + 5767168);
    u16* wq2t = (u16*)(ws + 5898240);
    u16* k1b  = (u16*)(ws + 6029312);
    u16* k2b  = (u16*)(ws + 7077888);
    u16* kd   = (u16*)(ws + 8126464);
    u16* kkd1 = (u16*)(ws + 9175040);
    u16* kkd2 = (u16*)(ws + 11272192);
    u16* vt1  = (u16*)(ws + 13369344);
    u16* vt2  = (u16*)(ws + 15466496);
    float* ebd = (float*)(ws + 17563648);

    float* out1 = (float*)d_out;
    float* out2 = out1 + (size_t)B_ * C_ * N_;

    hipLaunchKernelGGL(conv_all, dim3(11776), dim3(256), 0, stream,
                       y1, y2, wk1, wk2, wv1, wv2, wq1, wq2,
                       y1b, y2b, wk1b, wk2b, wv1b, wv2b, wq1t, wq2t);
    hipLaunchKernelGGL(gemm_gkgv, dim3(768), dim3(64), 0, stream,
                       y1b, y2b, wk1b, wk2b, wv1b, wv2b, bk1, bk2, bv1, bv2,
                       k1b, k2b, vt1, vt2);
    hipLaunchKernelGGL(kd_sub, dim3(2048), dim3(256), 0, stream, k1b, k2b, kd);
    hipLaunchKernelGGL(ebd_k, dim3(8), dim3(256), 0, stream, kd, bq1, bq2, ebd);
    hipLaunchKernelGGL(gemm_gkk, dim3(2, 8, 32), dim3(64), 0, stream,
                       kd, wq1t, wq2t, kkd1, kkd2);
    hipLaunchKernelGGL(main_attn, dim3(1024), dim3(256), 0, stream,
                       x1, x2, kkd1, kkd2, vt1, vt2, ebd, scale,
                       out1, out2);
}